// Round 8
// baseline (106267.944 us; speedup 1.0000x reference)
//
#include <hip/hip_runtime.h>
#include <hip/hip_fp16.h>
#include <math.h>

// Problem constants
#define BATCH 256
#define TSEQ  512
#define FEAT  64
#define NU1   256
#define NU2   128

// half2-element offsets inside workspace (packed fp16 weight planes)
// Pair-plane layout (R2-proven, L2-resident): plane[pair][col], half2=(row0,row0+1).
// GRU1: 160 pairs (64 x-rows then 256 h-rows) x 256 cols, per gate.
// GRU2: 192 pairs (256 h1-rows then 128 h2-rows) x 128 cols, per gate.
#define G1Z_OFF 0
#define G1R_OFF 40960
#define G1H_OFF 81920
#define G2Z_OFF 122880
#define G2R_OFF 147456
#define G2H_OFF 172032
#define TOTAL_H2 196608   // 786,432 bytes of d_ws

__device__ __forceinline__ float sigmoid_f(float v) {
    return 1.0f / (1.0f + __expf(-v));
}
__device__ __forceinline__ float tanh_f(float v) {
    float c = fminf(fmaxf(v, -15.0f), 15.0f);
    float e = __expf(2.0f * c);
    return (e - 1.0f) / (e + 1.0f);
}

// ---------------- weight packing (fp32 -> fp16 pair planes) ----------------
__global__ void pack_weights(const float* __restrict__ k1, const float* __restrict__ r1,
                             const float* __restrict__ k2, const float* __restrict__ r2,
                             __half2* __restrict__ ws)
{
    int idx = blockIdx.x * 256 + threadIdx.x;
    if (idx >= TOTAL_H2) return;
    float a, b;
    if (idx < G2Z_OFF) {
        int plane = idx / 40960;       // 0=z 1=r 2=h
        int rem   = idx % 40960;
        int pair  = rem >> 8;
        int col   = rem & 255;
        int g     = plane * 256 + col;
        int row0  = pair * 2;
        if (row0 < 64) { a = k1[row0 * 768 + g];        b = k1[(row0 + 1) * 768 + g]; }
        else           { a = r1[(row0 - 64) * 768 + g]; b = r1[(row0 - 63) * 768 + g]; }
    } else {
        int idx2  = idx - G2Z_OFF;
        int plane = idx2 / 24576;
        int rem   = idx2 % 24576;
        int pair  = rem >> 7;
        int col   = rem & 127;
        int g     = plane * 128 + col;
        int row0  = pair * 2;
        if (row0 < 256) { a = k2[row0 * 384 + g];         b = k2[(row0 + 1) * 384 + g]; }
        else            { a = r2[(row0 - 256) * 384 + g]; b = r2[(row0 - 255) * 384 + g]; }
    }
    __half2 h;
    h.x = __float2half_rn(a);
    h.y = __float2half_rn(b);
    ws[idx] = h;
}

// acc += w.lo * x0 + w.hi * x1   (fp16 weight, fp32 data/accum)
__device__ __forceinline__ void fma2(float& acc, __half2 w, float x0, float x1) {
    acc = fmaf(__half2float(__low2half(w)),  x0, acc);
    acc = fmaf(__half2float(__high2half(w)), x1, acc);
}

// Streamed K-segment: NPAIRS pairs, 3 gate planes, BLKP=2 register pipeline
// (6 loads in flight, 12 transient half2 regs — sized for the 256-VGPR budget).
template <int COLS, int NPAIRS>
__device__ __forceinline__ void seg(const __half2* __restrict__ pz,
                                    const __half2* __restrict__ pr,
                                    const __half2* __restrict__ ph,
                                    const float* __restrict__ s0,
                                    float& az, float& ar, float& a3)
{
    constexpr int BLKP = 2;
    constexpr int NB = NPAIRS / BLKP;
    __half2 bz[2][BLKP], br[2][BLKP], bh[2][BLKP];
    #pragma unroll
    for (int q = 0; q < BLKP; ++q) {
        bz[0][q] = pz[q * COLS]; br[0][q] = pr[q * COLS]; bh[0][q] = ph[q * COLS];
    }
    #pragma unroll
    for (int b = 0; b < NB; ++b) {
        const int cur = b & 1, nxt = cur ^ 1;
        if (b + 1 < NB) {
            const __half2* z2 = pz + (b + 1) * BLKP * COLS;
            const __half2* r2 = pr + (b + 1) * BLKP * COLS;
            const __half2* h2 = ph + (b + 1) * BLKP * COLS;
            #pragma unroll
            for (int q = 0; q < BLKP; ++q) {
                bz[nxt][q] = z2[q * COLS]; br[nxt][q] = r2[q * COLS]; bh[nxt][q] = h2[q * COLS];
            }
        }
        #pragma unroll
        for (int q = 0; q < BLKP; ++q) {
            const int i0 = (b * BLKP + q) * 2;
            const float2 v0 = *(const float2*)(s0 + i0);
            fma2(az, bz[cur][q], v0.x, v0.y);
            fma2(ar, br[cur][q], v0.x, v0.y);
            fma2(a3, bh[cur][q], v0.x, v0.y);
        }
    }
}

// 256 WGs x 512 threads, one batch row per WG. GRU1 recurrent weights live in
// registers (192 VGPRs/thread, loaded once); GRU1-x + GRU2 streamed from L2.
// __launch_bounds__(512,1): 256-VGPR cap — REQUIRED for the persistent set
// (R7's (512,2) capped at 128 and spilled 78 GB/launch of scratch traffic).
__global__ __launch_bounds__(512, 1)
void gru_fused(const float* __restrict__ x,
               const float* __restrict__ b1, const float* __restrict__ b2,
               const float* __restrict__ w3, const float* __restrict__ b3,
               const float* __restrict__ w4, const float* __restrict__ b4,
               const float* __restrict__ w5, const float* __restrict__ b5,
               const __half2* __restrict__ wp,
               float* __restrict__ out)
{
    __shared__ __align__(16) float h1[2][NU1];   // double-buffered
    __shared__ __align__(16) float h2[2][NU2];
    __shared__ __align__(16) float xt[2][FEAT];
    __shared__ float d3[64];
    __shared__ float d4[32];

    const int tid = threadIdx.x;
    const int row = blockIdx.x;
    const int j   = tid >> 1;       // GRU1 column
    const int kh  = tid & 1;        // GRU1 K-half
    const int c2  = tid >> 2;       // GRU2 column
    const int kq  = tid & 3;        // GRU2 K-quarter

    for (int i = tid; i < 2 * NU1; i += 512) (&h1[0][0])[i] = 0.0f;
    for (int i = tid; i < 2 * NU2; i += 512) (&h2[0][0])[i] = 0.0f;

    // biases masked to the lane that owns the reduction seed
    const float m1 = (kh == 0) ? 1.0f : 0.0f;
    const float bz1  = (b1[j] + b1[768 + j]) * m1;
    const float br1  = (b1[256 + j] + b1[1024 + j]) * m1;
    const float bxh1 = b1[512 + j] * m1;
    const float brh1 = b1[1280 + j] * m1;
    const float m2 = (kq == 0) ? 1.0f : 0.0f;
    const float bz2  = (b2[c2] + b2[384 + c2]) * m2;
    const float br2  = (b2[128 + c2] + b2[512 + c2]) * m2;
    const float bxh2 = b2[256 + c2] * m2;
    const float brh2 = b2[640 + c2] * m2;

    // column-offset plane pointers
    const __half2* g1z = wp + G1Z_OFF + j;
    const __half2* g1r = wp + G1R_OFF + j;
    const __half2* g1h = wp + G1H_OFF + j;

    // ---- register-resident GRU1 recurrent weights: pairs 32+kh*64+p ----
    // (lane kh owns h rows kh*128..kh*128+127 of every gate column j)
    __half2 wz1[64], wr1[64], wh1[64];
    {
        const __half2* bzp = g1z + (32 + kh * 64) * 256;
        const __half2* brp = g1r + (32 + kh * 64) * 256;
        const __half2* bhp = g1h + (32 + kh * 64) * 256;
        #pragma unroll
        for (int p = 0; p < 64; ++p) {
            wz1[p] = bzp[p * 256]; wr1[p] = brp[p * 256]; wh1[p] = bhp[p * 256];
        }
    }
    // GRU1-x streamed pointers: 16 pairs per lane (features kh*32..kh*32+31)
    const __half2* x1z = g1z + (kh * 16) * 256;
    const __half2* x1r = g1r + (kh * 16) * 256;
    const __half2* x1h = g1h + (kh * 16) * 256;
    // GRU2 streamed pointers: h1-part pairs kq*32+p; h2-part pairs 128+kq*16+p
    const __half2* g2zA = wp + G2Z_OFF + (kq * 32) * 128 + c2;
    const __half2* g2rA = wp + G2R_OFF + (kq * 32) * 128 + c2;
    const __half2* g2hA = wp + G2H_OFF + (kq * 32) * 128 + c2;
    const __half2* g2zB = wp + G2Z_OFF + (128 + kq * 16) * 128 + c2;
    const __half2* g2rB = wp + G2R_OFF + (128 + kq * 16) * 128 + c2;
    const __half2* g2hB = wp + G2H_OFF + (128 + kq * 16) * 128 + c2;

    if (tid < FEAT)
        xt[0][tid] = x[(size_t)row * TSEQ * FEAT + tid];
    __syncthreads();

    for (int t = 0; t < TSEQ; ++t) {
        const int cur = t & 1, nb = cur ^ 1;

        float xpre = 0.0f;
        if (t + 1 < TSEQ && tid < FEAT)
            xpre = x[(size_t)row * TSEQ * FEAT + (t + 1) * FEAT + tid];

        // ---------------- GRU1 ----------------
        float az = bz1, ar = br1, axh = bxh1, arh = brh1;
        // x-part: 16 pairs (features kh*32..kh*32+31), streamed
        seg<256, 16>(x1z, x1r, x1h, &xt[cur][kh * 32], az, ar, axh);
        // h-part from registers (64 pairs), input via float4 LDS reads
        #pragma unroll
        for (int q = 0; q < 32; ++q) {
            const float4 v = *(const float4*)(&h1[cur][kh * 128 + q * 4]);
            fma2(az,  wz1[2 * q], v.x, v.y); fma2(az,  wz1[2 * q + 1], v.z, v.w);
            fma2(ar,  wr1[2 * q], v.x, v.y); fma2(ar,  wr1[2 * q + 1], v.z, v.w);
            fma2(arh, wh1[2 * q], v.x, v.y); fma2(arh, wh1[2 * q + 1], v.z, v.w);
        }
        // intra-wave K-half reduction (lanes 2m / 2m+1)
        az  += __shfl_xor(az, 1);
        ar  += __shfl_xor(ar, 1);
        axh += __shfl_xor(axh, 1);
        arh += __shfl_xor(arh, 1);
        {
            const float z  = sigmoid_f(az);
            const float rg = sigmoid_f(ar);
            const float hh = tanh_f(axh + rg * arh);
            const float hn = z * h1[cur][j] + (1.0f - z) * hh;
            if (kh == 0) h1[nb][j] = hn;
        }
        if (t + 1 < TSEQ && tid < FEAT) xt[nb][tid] = xpre;
        __syncthreads();   // the one barrier: h1[nb] + xt[nb] visible

        // ---------------- GRU2 (streamed, K-quarter per lane) ----------------
        float az2 = bz2, ar2 = br2, axh2 = bxh2, arh2 = brh2;
        seg<128, 32>(g2zA, g2rA, g2hA, &h1[nb][kq * 64], az2, ar2, axh2);
        seg<128, 16>(g2zB, g2rB, g2hB, &h2[cur][kq * 32], az2, ar2, arh2);
        az2  += __shfl_xor(az2, 1);  az2  += __shfl_xor(az2, 2);
        ar2  += __shfl_xor(ar2, 1);  ar2  += __shfl_xor(ar2, 2);
        axh2 += __shfl_xor(axh2, 1); axh2 += __shfl_xor(axh2, 2);
        arh2 += __shfl_xor(arh2, 1); arh2 += __shfl_xor(arh2, 2);
        {
            const float z2v = sigmoid_f(az2);
            const float rg2 = sigmoid_f(ar2);
            const float hh2 = tanh_f(axh2 + rg2 * arh2);
            const float hn2 = z2v * h2[cur][c2] + (1.0f - z2v) * hh2;
            if (kq == 0) h2[nb][c2] = hn2;
        }
        // no second barrier: next step's barrier covers h2[nb] visibility
    }
    __syncthreads();   // h2[0] (written at t=511) visible for the head

    // ---------------- dense head: h2[0] -> 64 -> 32 -> 24 ----------------
    if (tid < 64) {
        float a = b3[tid];
        #pragma unroll 4
        for (int u = 0; u < NU2; ++u) a += h2[0][u] * w3[u * 64 + tid];
        d3[tid] = a;
    }
    __syncthreads();
    if (tid < 32) {
        float a = b4[tid];
        #pragma unroll 4
        for (int u = 0; u < 64; ++u) a += d3[u] * w4[u * 32 + tid];
        d4[tid] = a;
    }
    __syncthreads();
    if (tid < 24) {
        float a = b5[tid];
        #pragma unroll 4
        for (int u = 0; u < 32; ++u) a += d4[u] * w5[u * 24 + tid];
        out[(size_t)row * 24 + tid] = a;
    }
}

extern "C" void kernel_launch(void* const* d_in, const int* in_sizes, int n_in,
                              void* d_out, int out_size, void* d_ws, size_t ws_size,
                              hipStream_t stream) {
    (void)in_sizes; (void)n_in; (void)ws_size; (void)out_size;
    const float* x  = (const float*)d_in[0];
    const float* k1 = (const float*)d_in[1];
    const float* r1 = (const float*)d_in[2];
    const float* b1 = (const float*)d_in[3];
    const float* k2 = (const float*)d_in[4];
    const float* r2 = (const float*)d_in[5];
    const float* b2 = (const float*)d_in[6];
    const float* w3 = (const float*)d_in[7];
    const float* b3 = (const float*)d_in[8];
    const float* w4 = (const float*)d_in[9];
    const float* b4 = (const float*)d_in[10];
    const float* w5 = (const float*)d_in[11];
    const float* b5 = (const float*)d_in[12];
    float* out = (float*)d_out;
    __half2* wp = (__half2*)d_ws;

    hipLaunchKernelGGL(pack_weights, dim3((TOTAL_H2 + 255) / 256), dim3(256), 0, stream,
                       k1, r1, k2, r2, wp);
    hipLaunchKernelGGL(gru_fused, dim3(BATCH), dim3(512), 0, stream,
                       x, b1, b2, w3, b3, w4, b4, w5, b5, wp, out);
}

// Round 9
// 57992.444 us; speedup vs baseline: 1.8324x; 1.8324x over previous
//
#include <hip/hip_runtime.h>
#include <hip/hip_fp16.h>
#include <math.h>

// Problem constants
#define BATCH 256
#define TSEQ  512
#define FEAT  64
#define NU1   256
#define NU2   128

// Packed fp16 weight planes in d_ws, "virtual column" layout:
//   plane[pslot][vc], element = plane_base + pslot*1024 + vc   (half2 units)
// GRU1 (3 planes, 40 pslots, vc = j*4+kq):
//   pslot 0..7   -> x-part pair  kq*8  + pslot   (x rows kq*16 + 2q)
//   pslot 8..39  -> h-part pair  32 + kq*32 + (pslot-8)  (h rows kq*64 + 2q)
// GRU2 (3 planes, 24 pslots, vc = c2*8+ko):
//   pslot 0..15  -> h1 pair ko*16 + pslot        (h1 rows ko*32 + 2q)
//   pslot 16..23 -> h2 pair 128 + ko*8 + (pslot-16) (h2 rows ko*16 + 2q)
// Every wave-load of plane[pslot][tid] is 64 consecutive half2 = 256B coalesced.
#define G1Z_OFF 0
#define G1R_OFF 40960
#define G1H_OFF 81920
#define G2Z_OFF 122880
#define G2R_OFF 147456
#define G2H_OFF 172032
#define TOTAL_H2 196608   // 786,432 bytes of d_ws

// Bank-padded LDS layout for h-state: row r -> (r>>6)*68 + (r&63)
// (68-float segment stride => kq segments hit banks {0,4,8,12}: conflict-free)
#define SEGP 68

__device__ __forceinline__ int pphys(int r) { return (r >> 6) * SEGP + (r & 63); }

__device__ __forceinline__ float sigmoid_f(float v) {
    return 1.0f / (1.0f + __expf(-v));
}
__device__ __forceinline__ float tanh_f(float v) {
    float c = fminf(fmaxf(v, -15.0f), 15.0f);
    float e = __expf(2.0f * c);
    return (e - 1.0f) / (e + 1.0f);
}

// ---------------- weight packing (fp32 -> fp16 vc planes) ----------------
__global__ void pack_weights(const float* __restrict__ k1, const float* __restrict__ r1,
                             const float* __restrict__ k2, const float* __restrict__ r2,
                             __half2* __restrict__ ws)
{
    int idx = blockIdx.x * 256 + threadIdx.x;
    if (idx >= TOTAL_H2) return;
    float a, b;
    if (idx < G2Z_OFF) {
        // GRU1: 3 x [40][1024]
        int plane = idx / 40960;
        int rem   = idx % 40960;
        int pslot = rem >> 10;
        int vc    = rem & 1023;
        int j     = vc >> 2;
        int kq    = vc & 3;
        int g     = plane * 256 + j;
        int pair  = (pslot < 8) ? (kq * 8 + pslot) : (32 + kq * 32 + (pslot - 8));
        int row0  = pair * 2;
        if (row0 < 64) { a = k1[row0 * 768 + g];        b = k1[(row0 + 1) * 768 + g]; }
        else           { a = r1[(row0 - 64) * 768 + g]; b = r1[(row0 - 63) * 768 + g]; }
    } else {
        // GRU2: 3 x [24][1024]
        int idx2  = idx - G2Z_OFF;
        int plane = idx2 / 24576;
        int rem   = idx2 % 24576;
        int pslot = rem >> 10;
        int vc    = rem & 1023;
        int c2    = vc >> 3;
        int ko    = vc & 7;
        int g     = plane * 128 + c2;
        int pair  = (pslot < 16) ? (ko * 16 + pslot) : (128 + ko * 8 + (pslot - 16));
        int row0  = pair * 2;
        if (row0 < 256) { a = k2[row0 * 384 + g];         b = k2[(row0 + 1) * 384 + g]; }
        else            { a = r2[(row0 - 256) * 384 + g]; b = r2[(row0 - 255) * 384 + g]; }
    }
    __half2 h;
    h.x = __float2half_rn(a);
    h.y = __float2half_rn(b);
    ws[idx] = h;
}

// acc += w.lo * x0 + w.hi * x1   (fp16 weight, fp32 data/accum)
__device__ __forceinline__ void fma2(float& acc, __half2 w, float x0, float x1) {
    acc = fmaf(__half2float(__low2half(w)),  x0, acc);
    acc = fmaf(__half2float(__high2half(w)), x1, acc);
}

// Streamed K-segment over NP pslots (stride 1024), BLKP-deep pipeline.
// Input: float2 at s[2q] for pslot-relative q.
template <int NP, int BLKP>
__device__ __forceinline__ void seg(const __half2* __restrict__ pz,
                                    const __half2* __restrict__ pr,
                                    const __half2* __restrict__ ph,
                                    const float* __restrict__ s,
                                    float& az, float& ar, float& a3)
{
    constexpr int NB = NP / BLKP;
    __half2 bz[2][BLKP], br[2][BLKP], bh[2][BLKP];
    #pragma unroll
    for (int q = 0; q < BLKP; ++q) {
        bz[0][q] = pz[q * 1024]; br[0][q] = pr[q * 1024]; bh[0][q] = ph[q * 1024];
    }
    #pragma unroll
    for (int b = 0; b < NB; ++b) {
        const int cur = b & 1, nxt = cur ^ 1;
        if (b + 1 < NB) {
            const __half2* z2 = pz + (b + 1) * BLKP * 1024;
            const __half2* r2 = pr + (b + 1) * BLKP * 1024;
            const __half2* h2 = ph + (b + 1) * BLKP * 1024;
            #pragma unroll
            for (int q = 0; q < BLKP; ++q) {
                bz[nxt][q] = z2[q * 1024]; br[nxt][q] = r2[q * 1024]; bh[nxt][q] = h2[q * 1024];
            }
        }
        #pragma unroll
        for (int q = 0; q < BLKP; ++q) {
            const float2 v = *(const float2*)(s + 2 * (b * BLKP + q));
            fma2(az, bz[cur][q], v.x, v.y);
            fma2(ar, br[cur][q], v.x, v.y);
            fma2(a3, bh[cur][q], v.x, v.y);
        }
    }
}

// 256 WGs x 1024 threads (16 waves/CU), one batch row per WG.
// GRU1: col j = tid>>2, K-quarter kq = tid&3 (shfl_xor 1,2 reduce).
// GRU2: col c2 = tid>>3, K-eighth  ko = tid&7 (shfl_xor 1,2,4 reduce).
__global__ __launch_bounds__(1024, 1)
void gru_fused(const float* __restrict__ x,
               const float* __restrict__ b1, const float* __restrict__ b2,
               const float* __restrict__ w3, const float* __restrict__ b3,
               const float* __restrict__ w4, const float* __restrict__ b4,
               const float* __restrict__ w5, const float* __restrict__ b5,
               const __half2* __restrict__ wp,
               float* __restrict__ out)
{
    __shared__ __align__(16) float h1s[2][4 * SEGP];   // 256 rows, padded
    __shared__ __align__(16) float h2s[2][2 * SEGP];   // 128 rows, padded
    __shared__ __align__(16) float xt[2][FEAT];
    __shared__ float d3[64];
    __shared__ float d4[32];

    const int tid = threadIdx.x;
    const int row = blockIdx.x;
    const int j   = tid >> 2;
    const int kq  = tid & 3;
    const int c2  = tid >> 3;
    const int ko  = tid & 7;

    for (int i = tid; i < 2 * 4 * SEGP; i += 1024) (&h1s[0][0])[i] = 0.0f;
    for (int i = tid; i < 2 * 2 * SEGP; i += 1024) (&h2s[0][0])[i] = 0.0f;

    // biases seeded on the owning reduction lane
    const float m1 = (kq == 0) ? 1.0f : 0.0f;
    const float bz1  = (b1[j] + b1[768 + j]) * m1;
    const float br1  = (b1[256 + j] + b1[1024 + j]) * m1;
    const float bxh1 = b1[512 + j] * m1;
    const float brh1 = b1[1280 + j] * m1;
    const float m2 = (ko == 0) ? 1.0f : 0.0f;
    const float bz2  = (b2[c2] + b2[384 + c2]) * m2;
    const float br2  = (b2[128 + c2] + b2[512 + c2]) * m2;
    const float bxh2 = b2[256 + c2] * m2;
    const float brh2 = b2[640 + c2] * m2;

    // weight stream pointers (vc == tid)
    const __half2* p1z = wp + G1Z_OFF + tid;
    const __half2* p1r = wp + G1R_OFF + tid;
    const __half2* p1h = wp + G1H_OFF + tid;
    const __half2* p2z = wp + G2Z_OFF + tid;
    const __half2* p2r = wp + G2R_OFF + tid;
    const __half2* p2h = wp + G2H_OFF + tid;

    // LDS input base offsets (see layout comments)
    const int xb   = kq * 16;                               // xt rows kq*16
    const int h1b  = kq * SEGP;                             // h1 rows kq*64
    const int gcb  = (ko >> 1) * SEGP + (ko & 1) * 32;      // h1 rows ko*32
    const int gdb  = (ko >> 2) * SEGP + (ko & 3) * 16;      // h2 rows ko*16
    const int pj   = pphys(j);
    const int pc2  = pphys(c2);

    if (tid < FEAT)
        xt[0][tid] = x[(size_t)row * TSEQ * FEAT + tid];
    __syncthreads();

    for (int t = 0; t < TSEQ; ++t) {
        const int cur = t & 1, nb = cur ^ 1;

        float xpre = 0.0f;
        if (t + 1 < TSEQ && tid < FEAT)
            xpre = x[(size_t)row * TSEQ * FEAT + (t + 1) * FEAT + tid];

        // ---------------- GRU1 ----------------
        float az = bz1, ar = br1, axh = bxh1, arh = brh1;
        seg<8, 4>(p1z, p1r, p1h, &xt[cur][xb], az, ar, axh);                 // x-part
        seg<32, 8>(p1z + 8 * 1024, p1r + 8 * 1024, p1h + 8 * 1024,
                   &h1s[cur][h1b], az, ar, arh);                             // h-part
        az  += __shfl_xor(az, 1);  az  += __shfl_xor(az, 2);
        ar  += __shfl_xor(ar, 1);  ar  += __shfl_xor(ar, 2);
        axh += __shfl_xor(axh, 1); axh += __shfl_xor(axh, 2);
        arh += __shfl_xor(arh, 1); arh += __shfl_xor(arh, 2);
        {
            const float z  = sigmoid_f(az);
            const float rg = sigmoid_f(ar);
            const float hh = tanh_f(axh + rg * arh);
            const float hn = z * h1s[cur][pj] + (1.0f - z) * hh;
            if (kq == 0) h1s[nb][pj] = hn;
        }
        if (t + 1 < TSEQ && tid < FEAT) xt[nb][tid] = xpre;
        __syncthreads();   // the one barrier: h1s[nb] + xt[nb] visible

        // ---------------- GRU2 ----------------
        float az2 = bz2, ar2 = br2, axh2 = bxh2, arh2 = brh2;
        seg<16, 8>(p2z, p2r, p2h, &h1s[nb][gcb], az2, ar2, axh2);            // h1-part
        seg<8, 4>(p2z + 16 * 1024, p2r + 16 * 1024, p2h + 16 * 1024,
                  &h2s[cur][gdb], az2, ar2, arh2);                           // h2-part
        az2  += __shfl_xor(az2, 1);  az2  += __shfl_xor(az2, 2);  az2  += __shfl_xor(az2, 4);
        ar2  += __shfl_xor(ar2, 1);  ar2  += __shfl_xor(ar2, 2);  ar2  += __shfl_xor(ar2, 4);
        axh2 += __shfl_xor(axh2, 1); axh2 += __shfl_xor(axh2, 2); axh2 += __shfl_xor(axh2, 4);
        arh2 += __shfl_xor(arh2, 1); arh2 += __shfl_xor(arh2, 2); arh2 += __shfl_xor(arh2, 4);
        {
            const float z2v = sigmoid_f(az2);
            const float rg2 = sigmoid_f(ar2);
            const float hh2 = tanh_f(axh2 + rg2 * arh2);
            const float hn2 = z2v * h2s[cur][pc2] + (1.0f - z2v) * hh2;
            if (ko == 0) h2s[nb][pc2] = hn2;
        }
        // no second barrier: next step's barrier separates all hazards
    }
    __syncthreads();   // h2s[0] (written at t=511) visible for the head

    // ---------------- dense head: h2 -> 64 -> 32 -> 24 ----------------
    if (tid < 64) {
        float a = b3[tid];
        #pragma unroll 4
        for (int u = 0; u < NU2; ++u) a += h2s[0][pphys(u)] * w3[u * 64 + tid];
        d3[tid] = a;
    }
    __syncthreads();
    if (tid < 32) {
        float a = b4[tid];
        #pragma unroll 4
        for (int u = 0; u < 64; ++u) a += d3[u] * w4[u * 32 + tid];
        d4[tid] = a;
    }
    __syncthreads();
    if (tid < 24) {
        float a = b5[tid];
        #pragma unroll 4
        for (int u = 0; u < 32; ++u) a += d4[u] * w5[u * 24 + tid];
        out[(size_t)row * 24 + tid] = a;
    }
}

extern "C" void kernel_launch(void* const* d_in, const int* in_sizes, int n_in,
                              void* d_out, int out_size, void* d_ws, size_t ws_size,
                              hipStream_t stream) {
    (void)in_sizes; (void)n_in; (void)ws_size; (void)out_size;
    const float* x  = (const float*)d_in[0];
    const float* k1 = (const float*)d_in[1];
    const float* r1 = (const float*)d_in[2];
    const float* b1 = (const float*)d_in[3];
    const float* k2 = (const float*)d_in[4];
    const float* r2 = (const float*)d_in[5];
    const float* b2 = (const float*)d_in[6];
    const float* w3 = (const float*)d_in[7];
    const float* b3 = (const float*)d_in[8];
    const float* w4 = (const float*)d_in[9];
    const float* b4 = (const float*)d_in[10];
    const float* w5 = (const float*)d_in[11];
    const float* b5 = (const float*)d_in[12];
    float* out = (float*)d_out;
    __half2* wp = (__half2*)d_ws;

    hipLaunchKernelGGL(pack_weights, dim3((TOTAL_H2 + 255) / 256), dim3(256), 0, stream,
                       k1, r1, k2, r2, wp);
    hipLaunchKernelGGL(gru_fused, dim3(BATCH), dim3(1024), 0, stream,
                       x, b1, b2, w3, b3, w4, b4, w5, b5, wp, out);
}

// Round 10
// 38267.960 us; speedup vs baseline: 2.7769x; 1.5154x over previous
//
#include <hip/hip_runtime.h>
#include <hip/hip_fp16.h>
#include <math.h>

// Problem constants
#define BATCH 256
#define TSEQ  512
#define FEAT  64
#define NU1   256
#define NU2   128

typedef _Float16 h2v __attribute__((ext_vector_type(2)));

// Packed fp16 weights in d_ws, gate-interleaved "virtual column" layout
// (half2 units):
//   GRU1: W1[pair p 0..159][gate g 0..2][col vc 0..255]
//         p<32: x rows 2p,2p+1 (k1); p>=32: h1 rows 2(p-32).. (r1)
//         element offset = (p*3+g)*256 + vc
//   GRU2: W2[pp 0..95][gate g 0..2][vc 0..255], vc=(c2<<1)|kh
//         pp<64:  h1-pair kh*64+pp   (h1 rows kh*128 + 2*pp ..)
//         pp>=64: h2-pair kh*32+(pp-64) (h2 rows kh*64 + 2*(pp-64) ..)
//         element offset = W2OFF + (pp*3+g)*256 + vc
#define W2OFF  122880          // 160*3*256
#define TOTAL_H2 196608        // + 96*3*256 = 786,432 bytes of d_ws

__device__ __forceinline__ float sigmoid_f(float v) {
    return 1.0f / (1.0f + __expf(-v));
}
__device__ __forceinline__ float tanh_f(float v) {
    float c = fminf(fmaxf(v, -15.0f), 15.0f);
    float e = __expf(2.0f * c);
    return (e - 1.0f) / (e + 1.0f);
}

// ---------------- weight packing (fp32 -> fp16, gate-interleaved) ----------------
__global__ void pack_weights(const float* __restrict__ k1, const float* __restrict__ r1,
                             const float* __restrict__ k2, const float* __restrict__ r2,
                             h2v* __restrict__ ws)
{
    int idx = blockIdx.x * 256 + threadIdx.x;
    if (idx >= TOTAL_H2) return;
    float a, b;
    if (idx < W2OFF) {
        int p  = idx / 768;            // pair
        int rem = idx % 768;
        int g  = rem >> 8;             // gate
        int vc = rem & 255;            // col j
        int col = g * 256 + vc;        // in 768-wide
        if (p < 32) { int r0 = 2 * p;        a = k1[r0 * 768 + col]; b = k1[(r0 + 1) * 768 + col]; }
        else        { int r0 = 2 * (p - 32); a = r1[r0 * 768 + col]; b = r1[(r0 + 1) * 768 + col]; }
    } else {
        int i2 = idx - W2OFF;
        int pp = i2 / 768;
        int rem = i2 % 768;
        int g  = rem >> 8;
        int vc = rem & 255;
        int c2 = vc >> 1, kh = vc & 1;
        int col = g * 128 + c2;        // in 384-wide
        if (pp < 64) { int r0 = kh * 128 + 2 * pp;        a = k2[r0 * 384 + col]; b = k2[(r0 + 1) * 384 + col]; }
        else         { int r0 = kh * 64 + 2 * (pp - 64);  a = r2[r0 * 384 + col]; b = r2[(r0 + 1) * 384 + col]; }
    }
    h2v h;
    h[0] = (_Float16)a;
    h[1] = (_Float16)b;
    ws[idx] = h;
}

// acc += w.x*h.x + w.y*h.y  via v_dot2_f32_f16 (fp32 accumulate, exact products)
__device__ __forceinline__ void dot2(float& acc, h2v w, h2v h) {
#if __has_builtin(__builtin_amdgcn_fdot2)
    acc = __builtin_amdgcn_fdot2(w, h, acc, false);
#else
    acc = fmaf((float)w[0], (float)h[0], acc);
    acc = fmaf((float)w[1], (float)h[1], acc);
#endif
}

union hv4 { float4 f4; h2v h[4]; };

// NCHUNK chunks of 4 pairs. Chunk c reads 12 weight half2 (4 pairs x 3 gates,
// coalesced: lane vc at wbase+vc, offsets (pair*3+g)*256) and one 16B LDS
// vector of 4 input half2. Chunks < SPLIT accumulate gate-h into a3a, the
// rest into a3b (and read from srcB). Double-buffered: 12 loads in flight.
template <int NCHUNK, int SPLIT>
__device__ __forceinline__ void run_seg(const h2v* __restrict__ wbase,
                                        const __half* __restrict__ srcA,
                                        const __half* __restrict__ srcB,
                                        float& az, float& ar, float& a3a, float& a3b)
{
    h2v wb[2][12];
    #pragma unroll
    for (int i = 0; i < 4; ++i)
        #pragma unroll
        for (int g = 0; g < 3; ++g)
            wb[0][i * 3 + g] = wbase[(i * 3 + g) * 256];
    #pragma unroll
    for (int c = 0; c < NCHUNK; ++c) {
        const int cur = c & 1, nxt = cur ^ 1;
        if (c + 1 < NCHUNK) {
            const h2v* wn = wbase + ((c + 1) * 4 * 3) * 256;
            #pragma unroll
            for (int i = 0; i < 4; ++i)
                #pragma unroll
                for (int g = 0; g < 3; ++g)
                    wb[nxt][i * 3 + g] = wn[(i * 3 + g) * 256];
        }
        hv4 hv;
        if (c < SPLIT) hv.f4 = *(const float4*)(srcA + 8 * c);
        else           hv.f4 = *(const float4*)(srcB + 8 * (c - SPLIT));
        #pragma unroll
        for (int i = 0; i < 4; ++i) {
            dot2(az, wb[cur][i * 3 + 0], hv.h[i]);
            dot2(ar, wb[cur][i * 3 + 1], hv.h[i]);
            if (c < SPLIT) dot2(a3a, wb[cur][i * 3 + 2], hv.h[i]);
            else           dot2(a3b, wb[cur][i * 3 + 2], hv.h[i]);
        }
    }
}

// 256 WGs x 256 threads, one batch row per WG, one barrier per timestep.
// GRU1: thread = col j, full K (no reduction). GRU2: c2=tid>>1, kh=tid&1,
// uniform-shape K-halves, shfl_xor(1) reduce. State in LDS as fp16.
__global__ __launch_bounds__(256, 1)
void gru_fused(const float* __restrict__ x,
               const float* __restrict__ b1, const float* __restrict__ b2,
               const float* __restrict__ w3, const float* __restrict__ b3,
               const float* __restrict__ w4, const float* __restrict__ b4,
               const float* __restrict__ w5, const float* __restrict__ b5,
               const h2v* __restrict__ wp,
               float* __restrict__ out)
{
    // s1 = [x(64) ; h1(256)] combined input vector for GRU1 (fp16), dbuf
    __shared__ __align__(16) __half s1[2][320];
    __shared__ __align__(16) __half s2h1[2][256];   // h1 copy for GRU2
    __shared__ __align__(16) __half s2h2[2][128];   // h2 state
    __shared__ float d3[64];
    __shared__ float d4[32];

    const int tid = threadIdx.x;
    const int row = blockIdx.x;
    const int j   = tid;            // GRU1 column
    const int c2  = tid >> 1;       // GRU2 column
    const int kh  = tid & 1;        // GRU2 K-half

    for (int i = tid; i < 2 * 320; i += 256) (&s1[0][0])[i] = __float2half_rn(0.0f);
    for (int i = tid; i < 2 * 256; i += 256) (&s2h1[0][0])[i] = __float2half_rn(0.0f);
    for (int i = tid; i < 2 * 128; i += 256) (&s2h2[0][0])[i] = __float2half_rn(0.0f);

    // GRU1 biases (full-K per thread: plain)
    const float bz1  = b1[j] + b1[768 + j];
    const float br1  = b1[256 + j] + b1[1024 + j];
    const float bxh1 = b1[512 + j];
    const float brh1 = b1[1280 + j];
    // GRU2 biases seeded on kh==0 lane
    const float m2 = (kh == 0) ? 1.0f : 0.0f;
    const float bz2  = (b2[c2] + b2[384 + c2]) * m2;
    const float br2  = (b2[128 + c2] + b2[512 + c2]) * m2;
    const float bxh2 = b2[256 + c2] * m2;
    const float brh2 = b2[640 + c2] * m2;

    const h2v* w1 = wp + tid;            // GRU1 stream, vc = j
    const h2v* w2 = wp + W2OFF + tid;    // GRU2 stream, vc = (c2<<1)|kh

    if (tid < FEAT)
        s1[0][tid] = __float2half_rn(x[(size_t)row * TSEQ * FEAT + tid]);
    __syncthreads();

    for (int t = 0; t < TSEQ; ++t) {
        const int cur = t & 1, nb = cur ^ 1;

        float xpre = 0.0f;
        if (t + 1 < TSEQ && tid < FEAT)
            xpre = x[(size_t)row * TSEQ * FEAT + (t + 1) * FEAT + tid];

        // ---------------- GRU1: one continuous 160-pair stream ----------------
        // chunks 0..7 = x-part (gate-h -> axh), 8..39 = h-part (gate-h -> arh);
        // LDS source is uniform: s1[cur] at halves 8c.
        float az = bz1, ar = br1, axh = bxh1, arh = brh1;
        run_seg<40, 8>(w1, &s1[cur][0], &s1[cur][64], az, ar, axh, arh);
        {
            const float z  = sigmoid_f(az);
            const float rg = sigmoid_f(ar);
            const float hh = tanh_f(axh + rg * arh);
            const float hn = z * __half2float(s1[cur][64 + j]) + (1.0f - z) * hh;
            const __half hn_h = __float2half_rn(hn);
            s1[nb][64 + j] = hn_h;      // GRU1's own next-step input
            s2h1[nb][j]   = hn_h;       // GRU2's input this step
        }
        if (t + 1 < TSEQ && tid < FEAT) s1[nb][tid] = __float2half_rn(xpre);
        __syncthreads();   // the one barrier: s1[nb], s2h1[nb] visible

        // ---------------- GRU2: 96 pairs (64 h1 + 32 h2), K-half per lane ----------------
        float az2 = bz2, ar2 = br2, axh2 = bxh2, arh2 = brh2;
        run_seg<24, 16>(w2, &s2h1[nb][kh * 128], &s2h2[cur][kh * 64],
                        az2, ar2, axh2, arh2);
        az2  += __shfl_xor(az2, 1);
        ar2  += __shfl_xor(ar2, 1);
        axh2 += __shfl_xor(axh2, 1);
        arh2 += __shfl_xor(arh2, 1);
        {
            const float z2v = sigmoid_f(az2);
            const float rg2 = sigmoid_f(ar2);
            const float hh2 = tanh_f(axh2 + rg2 * arh2);
            const float hn2 = z2v * __half2float(s2h2[cur][c2]) + (1.0f - z2v) * hh2;
            if (kh == 0) s2h2[nb][c2] = __float2half_rn(hn2);
        }
        // no second barrier: next step's barrier separates all hazards
        // (s2h2[nb] reads at t+1 happen after barrier(t+1); s2h2 writes at t+1
        //  target buffer [cur] whose readers finished before barrier(t+1))
    }
    __syncthreads();   // final h2 (buffer 0, written at t=511) visible

    // ---------------- dense head: h2 -> 64 -> 32 -> 24 ----------------
    if (tid < 64) {
        float a = b3[tid];
        #pragma unroll 4
        for (int u = 0; u < NU2; ++u) a += __half2float(s2h2[0][u]) * w3[u * 64 + tid];
        d3[tid] = a;
    }
    __syncthreads();
    if (tid < 32) {
        float a = b4[tid];
        #pragma unroll 4
        for (int u = 0; u < 64; ++u) a += d3[u] * w4[u * 32 + tid];
        d4[tid] = a;
    }
    __syncthreads();
    if (tid < 24) {
        float a = b5[tid];
        #pragma unroll 4
        for (int u = 0; u < 32; ++u) a += d4[u] * w5[u * 24 + tid];
        out[(size_t)row * 24 + tid] = a;
    }
}

extern "C" void kernel_launch(void* const* d_in, const int* in_sizes, int n_in,
                              void* d_out, int out_size, void* d_ws, size_t ws_size,
                              hipStream_t stream) {
    (void)in_sizes; (void)n_in; (void)ws_size; (void)out_size;
    const float* x  = (const float*)d_in[0];
    const float* k1 = (const float*)d_in[1];
    const float* r1 = (const float*)d_in[2];
    const float* b1 = (const float*)d_in[3];
    const float* k2 = (const float*)d_in[4];
    const float* r2 = (const float*)d_in[5];
    const float* b2 = (const float*)d_in[6];
    const float* w3 = (const float*)d_in[7];
    const float* b3 = (const float*)d_in[8];
    const float* w4 = (const float*)d_in[9];
    const float* b4 = (const float*)d_in[10];
    const float* w5 = (const float*)d_in[11];
    const float* b5 = (const float*)d_in[12];
    float* out = (float*)d_out;
    h2v* wp = (h2v*)d_ws;

    hipLaunchKernelGGL(pack_weights, dim3((TOTAL_H2 + 255) / 256), dim3(256), 0, stream,
                       k1, r1, k2, r2, wp);
    hipLaunchKernelGGL(gru_fused, dim3(BATCH), dim3(256), 0, stream,
                       x, b1, b2, w3, b3, w4, b4, w5, b5, wp, out);
}